// Round 5
// baseline (628.799 us; speedup 1.0000x reference)
//
#include <hip/hip_runtime.h>

// LSTM decoder: B=1024, H=16, 4H=64 gates, T=128 steps x 16 cells = 2048
// strictly-serial cell evaluations per batch chain.
//
// Round-5 mapping: ONE WORKGROUP (128 threads = 2 waves) PER CHAIN.
//   wave 0: computes gates (i,f) for hidden k = lane&15 (packed float2 dot)
//   wave 1: computes gates (g,o)
// -> 2048 waves on 1024 SIMDs = 2 waves/SIMD, so one chain's LDS/barrier
// stalls are filled by the co-resident chain (round 4: 25% stall at 1/SIMD).
// Gate exchange: lanes j<16 write their float2 gate pair into g4[t&1][k],
// ONE __syncthreads, all 128 lanes read float4 {i,f,g,o}. Parity double-
// buffering makes a second barrier unnecessary (next cell writes the other
// buffer, so it can never race this cell's readers).
// Both waves then redundantly compute c, tanh(c), h[k] and do an intra-wave
// h broadcast (round-4 trick: ds_write + 4x ds_read_b128, wave_barrier only).
// Dots are float2-packed to target v_pk_fma_f32 (full-rate packed FP32);
// if the compiler scalarizes, it degrades to round-4's scalar FMA count.
// Activation scaling (-log2e; -2log2e for g) folded into weight copies.

typedef float f32x2 __attribute__((ext_vector_type(2)));

#define B_ 1024
#define A_ 16
#define T_ 128
#define R_ 128
#define H_ 16

__global__ __launch_bounds__(128) void lstm_decoder_kernel(
    const float* __restrict__ y,     // (B,16)
    const float* __restrict__ u,     // (B,128)
    const float* __restrict__ W_ih,  // (64,1)
    const float* __restrict__ W_hh,  // (64,16)
    const float* __restrict__ b_ih,  // (64)
    const float* __restrict__ b_hh,  // (64)
    const float* __restrict__ W_lin, // (1,16)
    const float* __restrict__ b_lin, // (1)
    const float* __restrict__ W_h0,  // (16,128)
    const float* __restrict__ b_h0,  // (16)
    const float* __restrict__ W_c0,  // (16,128)
    const float* __restrict__ b_c0,  // (16)
    float* __restrict__ out)         // (B,144)
{
    const int b   = blockIdx.x;      // batch chain
    const int tid = threadIdx.x;     // 0..127
    const int wv  = tid >> 6;        // 0 -> gates (i,f), 1 -> gates (g,o)
    const int j   = tid & 63;        // lane
    const int k   = j & 15;          // hidden index (4 copies per wave)

    __shared__ float lds_u[R_];
    __shared__ float lds_h[H_];
    __shared__ float lds_c[H_];
    __shared__ __attribute__((aligned(16))) float g4[2][H_][4];  // [parity][k][i,f,g,o]
    __shared__ __attribute__((aligned(16))) float hb[2][64];     // per-wave h broadcast

    // ---- stage u[b,:] (coalesced: 128 threads, 128 floats) ----
    lds_u[tid] = u[b * R_ + tid];
    __syncthreads();

    // ---- h0/c0 init: threads 0..15 -> h0[k], 16..31 -> c0[k] ----
    if (tid < 32) {
        const float* Wr = (tid < 16) ? (W_h0 + k * R_) : (W_c0 + k * R_);
        float acc = (tid < 16) ? b_h0[k] : b_c0[k];
        #pragma unroll
        for (int r = 0; r < R_; r += 4) {
            float4 wvv = *(const float4*)(Wr + r);
            float4 uv  = *(const float4*)(&lds_u[r]);
            acc = fmaf(wvv.x, uv.x, acc);
            acc = fmaf(wvv.y, uv.y, acc);
            acc = fmaf(wvv.z, uv.z, acc);
            acc = fmaf(wvv.w, uv.w, acc);
        }
        if (tid < 16) lds_h[k] = acc;
        else          lds_c[k] = acc;
    }
    __syncthreads();

    // ---- pre-scaled packed weights for this wave's two gates ----
    const float LOG2E = 1.4426950408889634f;
    const int   qa = 2 * wv, qb = 2 * wv + 1;      // wave0: i,f  wave1: g,o
    const float sa = (wv == 1) ? (-2.0f * LOG2E) : (-LOG2E);  // g is tanh
    const float sb = -LOG2E;
    const int   rowA = k + 16 * qa, rowB = k + 16 * qb;

    f32x2 w2[H_];
    {
        const float* ra = W_hh + rowA * H_;
        const float* rb = W_hh + rowB * H_;
        #pragma unroll
        for (int m = 0; m < H_; ++m) {
            f32x2 t; t.x = sa * ra[m]; t.y = sb * rb[m];
            w2[m] = t;
        }
    }
    f32x2 b2, wi2;
    b2.x  = sa * (b_ih[rowA] + b_hh[rowA]);
    b2.y  = sb * (b_ih[rowB] + b_hh[rowB]);
    wi2.x = sa * W_ih[rowA];
    wi2.y = sb * W_ih[rowB];
    const float cK = -2.0f * LOG2E;   // for tanh(c)

    float wl[H_];
    #pragma unroll
    for (int m = 0; m < H_; ++m) wl[m] = W_lin[m];
    const float bl = b_lin[0];

    // ---- replicated per-thread state ----
    float h[H_];
    #pragma unroll
    for (int m = 0; m < H_; ++m) h[m] = lds_h[m];
    float c = lds_c[k];

    float win[A_];
    #pragma unroll
    for (int t = 0; t < A_; ++t) win[t] = y[b * A_ + t];

    float pout0 = 0.f, pout1 = 0.f;

    for (int s = 0; s < T_; ++s) {
        #pragma unroll
        for (int t = 0; t < A_; ++t) {
            const float x = win[t];
            // ---- packed dot: this wave's two gates for hidden index k ----
            f32x2 x2; x2.x = x; x2.y = x;
            f32x2 a0 = __builtin_elementwise_fma(x2, wi2, b2);
            {
                f32x2 hm; hm.x = h[0]; hm.y = h[0];
                a0 = __builtin_elementwise_fma(hm, w2[0], a0);
            }
            f32x2 a1, a2, a3;
            { f32x2 hm; hm.x = h[1]; hm.y = h[1]; a1 = hm * w2[1]; }
            { f32x2 hm; hm.x = h[2]; hm.y = h[2]; a2 = hm * w2[2]; }
            { f32x2 hm; hm.x = h[3]; hm.y = h[3]; a3 = hm * w2[3]; }
            #pragma unroll
            for (int m = 4; m < H_; m += 4) {
                f32x2 h0v; h0v.x = h[m+0]; h0v.y = h[m+0];
                f32x2 h1v; h1v.x = h[m+1]; h1v.y = h[m+1];
                f32x2 h2v; h2v.x = h[m+2]; h2v.y = h[m+2];
                f32x2 h3v; h3v.x = h[m+3]; h3v.y = h[m+3];
                a0 = __builtin_elementwise_fma(h0v, w2[m+0], a0);
                a1 = __builtin_elementwise_fma(h1v, w2[m+1], a1);
                a2 = __builtin_elementwise_fma(h2v, w2[m+2], a2);
                a3 = __builtin_elementwise_fma(h3v, w2[m+3], a3);
            }
            f32x2 z2 = (a0 + a1) + (a2 + a3);

            // ---- this wave's two activations ----
            const float ea = __builtin_amdgcn_exp2f(z2.x);
            const float eb = __builtin_amdgcn_exp2f(z2.y);
            float act_a = __builtin_amdgcn_rcpf(1.0f + ea);
            const float act_b = __builtin_amdgcn_rcpf(1.0f + eb);
            if (wv == 1) act_a = fmaf(2.0f, act_a, -1.0f);   // g gate: tanh

            // ---- gate exchange (parity-double-buffered, ONE barrier) ----
            if (j < 16) {
                f32x2 pr; pr.x = act_a; pr.y = act_b;
                *(f32x2*)&g4[t & 1][k][2 * wv] = pr;
            }
            __syncthreads();
            const float4 gq = *(const float4*)&g4[t & 1][k][0]; // i,f,g,o

            // ---- redundant tail (both waves): c, tanh(c), h[k] ----
            c = fmaf(gq.y, c, gq.x * gq.z);
            const float ec = __builtin_amdgcn_exp2f(cK * c);              // e^{-2c}
            const float th = fmaf(2.0f, __builtin_amdgcn_rcpf(1.0f + ec), -1.0f);
            const float hk = gq.w * th;

            // ---- intra-wave h broadcast (no cross-wave sync needed) ----
            hb[wv][j] = hk;
            __builtin_amdgcn_wave_barrier();
            float4 h0q = *(const float4*)&hb[wv][0];
            float4 h1q = *(const float4*)&hb[wv][4];
            float4 h2q = *(const float4*)&hb[wv][8];
            float4 h3q = *(const float4*)&hb[wv][12];
            h[0]=h0q.x;  h[1]=h0q.y;  h[2]=h0q.z;  h[3]=h0q.w;
            h[4]=h1q.x;  h[5]=h1q.y;  h[6]=h1q.z;  h[7]=h1q.w;
            h[8]=h2q.x;  h[9]=h2q.y;  h[10]=h2q.z; h[11]=h2q.w;
            h[12]=h3q.x; h[13]=h3q.y; h[14]=h3q.z; h[15]=h3q.w;
            __builtin_amdgcn_wave_barrier();
        }
        // ---- pred + window slide (replicated; consumed 16 cells later) ----
        float p = bl;
        #pragma unroll
        for (int m = 0; m < H_; ++m) p = fmaf(h[m], wl[m], p);
        #pragma unroll
        for (int t = 0; t < A_ - 1; ++t) win[t] = win[t + 1];
        win[A_ - 1] = p;
        if (wv == 0) {
            if (s == j)      pout0 = p;
            if (s == j + 64) pout1 = p;
        }
    }

    // ---- output (wave 0 only): out[b,0:16]=y, out[b,16+s]=pred_s ----
    if (wv == 0) {
        if (j < A_) out[b * (A_ + T_) + j] = y[b * A_ + j];
        out[b * (A_ + T_) + A_ + j]      = pout0;
        out[b * (A_ + T_) + A_ + 64 + j] = pout1;
    }
}

extern "C" void kernel_launch(void* const* d_in, const int* in_sizes, int n_in,
                              void* d_out, int out_size, void* d_ws, size_t ws_size,
                              hipStream_t stream) {
    const float* y     = (const float*)d_in[0];
    const float* u     = (const float*)d_in[1];
    const float* W_ih  = (const float*)d_in[2];
    const float* W_hh  = (const float*)d_in[3];
    const float* b_ih  = (const float*)d_in[4];
    const float* b_hh  = (const float*)d_in[5];
    const float* W_lin = (const float*)d_in[6];
    const float* b_lin = (const float*)d_in[7];
    const float* W_h0  = (const float*)d_in[8];
    const float* b_h0  = (const float*)d_in[9];
    const float* W_c0  = (const float*)d_in[10];
    const float* b_c0  = (const float*)d_in[11];
    float* out = (float*)d_out;

    lstm_decoder_kernel<<<B_, 128, 0, stream>>>(
        y, u, W_ih, W_hh, b_ih, b_hh, W_lin, b_lin,
        W_h0, b_h0, W_c0, b_c0, out);
}

// Round 6
// 447.375 us; speedup vs baseline: 1.4055x; 1.4055x over previous
//
#include <hip/hip_runtime.h>

// LSTM decoder: B=1024, H=16, 4H=64 gates, T=128 steps x 16 cells = 2048
// strictly-serial cell evaluations per batch chain.
//
// Round-6 mapping: back to round-4's single wave per chain (1024 waves =
// 1/SIMD; round 5 proved cross-wave per-cell barriers are a net loss).
// Each lane kp=j&15 redundantly computes all 4 gates (i,f,g,o) of hidden
// index kp, so c[kp] and h[kp] are local. NEW: the per-cell h-broadcast is
// done with 15 DPP row_ror ops instead of the LDS write->read round trip
// (round-4's entire 153-cyc/cell stall). Every 16-lane DPP row holds the
// full h vector one-element-per-lane, so a row all-gather = 15 rotations;
// lanes consume h in rotated order against PER-LANE PRE-PERMUTED weights.
// Rotation direction is probed at runtime (rotate lane-id, compare), so we
// don't bet correctness on DPP direction conventions.
// Activation scaling (-log2e; -2log2e for g) folded into weight copies.

#define B_ 1024
#define A_ 16
#define T_ 128
#define R_ 128
#define H_ 16

template<int CTRL>
__device__ __forceinline__ float dpp_rotf(float v) {
    return __int_as_float(__builtin_amdgcn_update_dpp(
        0, __float_as_int(v), CTRL, 0xF, 0xF, true));
}

__global__ __launch_bounds__(64) void lstm_decoder_kernel(
    const float* __restrict__ y,     // (B,16)
    const float* __restrict__ u,     // (B,128)
    const float* __restrict__ W_ih,  // (64,1)
    const float* __restrict__ W_hh,  // (64,16)
    const float* __restrict__ b_ih,  // (64)
    const float* __restrict__ b_hh,  // (64)
    const float* __restrict__ W_lin, // (1,16)
    const float* __restrict__ b_lin, // (1)
    const float* __restrict__ W_h0,  // (16,128)
    const float* __restrict__ b_h0,  // (16)
    const float* __restrict__ W_c0,  // (16,128)
    const float* __restrict__ b_c0,  // (16)
    float* __restrict__ out)         // (B,144)
{
    const int b  = blockIdx.x;    // batch chain
    const int j  = threadIdx.x;   // lane 0..63
    const int kp = j & 15;        // hidden index this lane owns (4 row copies)

    __shared__ float lds_u[R_];
    __shared__ float lds_h[H_];
    __shared__ float lds_c[H_];

    // ---- stage u[b,:] to LDS (coalesced) ----
    lds_u[j]      = u[b * R_ + j];
    lds_u[j + 64] = u[b * R_ + j + 64];
    __syncthreads();

    // ---- h0 / c0 init: lanes 0..15 -> h0[kp], lanes 16..31 -> c0[kp] ----
    if (j < 32) {
        const float* Wr = (j < 16) ? (W_h0 + kp * R_) : (W_c0 + kp * R_);
        float acc = (j < 16) ? b_h0[kp] : b_c0[kp];
        #pragma unroll
        for (int r = 0; r < R_; r += 4) {
            float4 wv = *(const float4*)(Wr + r);
            float4 uv = *(const float4*)(&lds_u[r]);
            acc = fmaf(wv.x, uv.x, acc);
            acc = fmaf(wv.y, uv.y, acc);
            acc = fmaf(wv.z, uv.z, acc);
            acc = fmaf(wv.w, uv.w, acc);
        }
        if (j < 16) lds_h[kp] = acc;
        else        lds_c[kp] = acc;
    }

    // ---- probe DPP row_ror direction (no convention bet) ----
    // After ror:1, does lane kp hold (kp+1)&15 or (kp-1)&15 ?
    const int probe = __builtin_amdgcn_update_dpp(0, kp, 0x121, 0xF, 0xF, true);
    const bool plus = (probe == ((kp + 1) & 15));

    // ---- pre-scaled, PER-LANE-PERMUTED weights ----
    // w4[q][r] multiplies the h value that arrives at rotation step r,
    // which is h[(kp +/- r)&15] per the probed direction.
    const float LOG2E = 1.4426950408889634f;
    float w4[4][H_], b4[4], wi4[4], wlr[H_];
    #pragma unroll
    for (int q = 0; q < 4; ++q) {
        const float s = (q == 2) ? (-2.0f * LOG2E) : (-LOG2E);
        const int row = kp + 16 * q;
        b4[q]  = s * (b_ih[row] + b_hh[row]);
        wi4[q] = s * W_ih[row];
        #pragma unroll
        for (int r = 0; r < H_; ++r) {
            const int idx = plus ? ((kp + r) & 15) : ((kp - r) & 15);
            w4[q][r] = s * W_hh[row * H_ + idx];
        }
    }
    #pragma unroll
    for (int r = 0; r < H_; ++r) {
        const int idx = plus ? ((kp + r) & 15) : ((kp - r) & 15);
        wlr[r] = W_lin[idx];
    }
    const float cK = -2.0f * LOG2E;   // for tanh(c)
    const float bl = b_lin[0];

    __syncthreads();
    float hk = lds_h[kp];     // this lane's hidden element
    float c  = lds_c[kp];

    float win[A_];
    #pragma unroll
    for (int t = 0; t < A_; ++t) win[t] = y[b * A_ + t];

    float pout0 = 0.f, pout1 = 0.f;

    for (int s = 0; s < T_; ++s) {
        #pragma unroll
        for (int t = 0; t < A_; ++t) {
            const float x = win[t];
            // ---- 4 gate dots via DPP row all-gather (no LDS) ----
            float z0[4], z1[4];
            #pragma unroll
            for (int q = 0; q < 4; ++q)
                z0[q] = fmaf(hk, w4[q][0], fmaf(x, wi4[q], b4[q]));
            {
                const float hr = dpp_rotf<0x121>(hk);
                z1[0] = hr * w4[0][1]; z1[1] = hr * w4[1][1];
                z1[2] = hr * w4[2][1]; z1[3] = hr * w4[3][1];
            }
#define CELL_ROT(R, CTRL, ACC)                                        \
            {                                                         \
                const float hr = dpp_rotf<CTRL>(hk);                  \
                ACC[0] = fmaf(hr, w4[0][R], ACC[0]);                  \
                ACC[1] = fmaf(hr, w4[1][R], ACC[1]);                  \
                ACC[2] = fmaf(hr, w4[2][R], ACC[2]);                  \
                ACC[3] = fmaf(hr, w4[3][R], ACC[3]);                  \
            }
            CELL_ROT(2,  0x122, z0)
            CELL_ROT(3,  0x123, z1)
            CELL_ROT(4,  0x124, z0)
            CELL_ROT(5,  0x125, z1)
            CELL_ROT(6,  0x126, z0)
            CELL_ROT(7,  0x127, z1)
            CELL_ROT(8,  0x128, z0)
            CELL_ROT(9,  0x129, z1)
            CELL_ROT(10, 0x12A, z0)
            CELL_ROT(11, 0x12B, z1)
            CELL_ROT(12, 0x12C, z0)
            CELL_ROT(13, 0x12D, z1)
            CELL_ROT(14, 0x12E, z0)
            CELL_ROT(15, 0x12F, z1)
#undef CELL_ROT
            const float zi = z0[0] + z1[0];
            const float zf = z0[1] + z1[1];
            const float zg = z0[2] + z1[2];
            const float zo = z0[3] + z1[3];

            // ---- activations (pre-scaled: exp2 gives e^{-z} / e^{-2z}) ----
            const float iv = __builtin_amdgcn_rcpf(1.0f + __builtin_amdgcn_exp2f(zi));
            const float fv = __builtin_amdgcn_rcpf(1.0f + __builtin_amdgcn_exp2f(zf));
            const float gg = fmaf(2.0f, __builtin_amdgcn_rcpf(1.0f + __builtin_amdgcn_exp2f(zg)), -1.0f);
            const float ov = __builtin_amdgcn_rcpf(1.0f + __builtin_amdgcn_exp2f(zo));

            // ---- c, h[kp] update (all local) ----
            c = fmaf(fv, c, iv * gg);
            const float ec = __builtin_amdgcn_exp2f(cK * c);                       // e^{-2c}
            const float th = fmaf(2.0f, __builtin_amdgcn_rcpf(1.0f + ec), -1.0f);  // tanh(c)
            hk = ov * th;
        }

        // ---- pred = h . W_lin + b_lin via one more DPP all-gather ----
        float pa = fmaf(hk, wlr[0], bl);
        float pb;
        {
            const float hr = dpp_rotf<0x121>(hk);
            pb = hr * wlr[1];
        }
#define PRED_ROT(R, CTRL, ACC)                                        \
        {                                                             \
            const float hr = dpp_rotf<CTRL>(hk);                      \
            ACC = fmaf(hr, wlr[R], ACC);                              \
        }
        PRED_ROT(2,  0x122, pa)
        PRED_ROT(3,  0x123, pb)
        PRED_ROT(4,  0x124, pa)
        PRED_ROT(5,  0x125, pb)
        PRED_ROT(6,  0x126, pa)
        PRED_ROT(7,  0x127, pb)
        PRED_ROT(8,  0x128, pa)
        PRED_ROT(9,  0x129, pb)
        PRED_ROT(10, 0x12A, pa)
        PRED_ROT(11, 0x12B, pb)
        PRED_ROT(12, 0x12C, pa)
        PRED_ROT(13, 0x12D, pb)
        PRED_ROT(14, 0x12E, pa)
        PRED_ROT(15, 0x12F, pb)
#undef PRED_ROT
        const float p = pa + pb;

        // ---- window slide + pred stash ----
        #pragma unroll
        for (int t = 0; t < A_ - 1; ++t) win[t] = win[t + 1];
        win[A_ - 1] = p;
        if (s == j)      pout0 = p;
        if (s == j + 64) pout1 = p;
    }

    // ---- output: out[b,0:16]=y[b,:], out[b,16+s]=pred_s ----
    if (j < A_) out[b * (A_ + T_) + j] = y[b * A_ + j];
    out[b * (A_ + T_) + A_ + j]      = pout0;
    out[b * (A_ + T_) + A_ + 64 + j] = pout1;
}

extern "C" void kernel_launch(void* const* d_in, const int* in_sizes, int n_in,
                              void* d_out, int out_size, void* d_ws, size_t ws_size,
                              hipStream_t stream) {
    const float* y     = (const float*)d_in[0];
    const float* u     = (const float*)d_in[1];
    const float* W_ih  = (const float*)d_in[2];
    const float* W_hh  = (const float*)d_in[3];
    const float* b_ih  = (const float*)d_in[4];
    const float* b_hh  = (const float*)d_in[5];
    const float* W_lin = (const float*)d_in[6];
    const float* b_lin = (const float*)d_in[7];
    const float* W_h0  = (const float*)d_in[8];
    const float* b_h0  = (const float*)d_in[9];
    const float* W_c0  = (const float*)d_in[10];
    const float* b_c0  = (const float*)d_in[11];
    float* out = (float*)d_out;

    lstm_decoder_kernel<<<B_, 64, 0, stream>>>(
        y, u, W_ih, W_hh, b_ih, b_hh, W_lin, b_lin,
        W_h0, b_h0, W_c0, b_c0, out);
}

// Round 7
// 341.135 us; speedup vs baseline: 1.8433x; 1.3114x over previous
//
#include <hip/hip_runtime.h>

// LSTM decoder: B=1024, H=16, 4H=64 gates, T=128 steps x 16 cells = 2048
// strictly-serial cell evaluations per batch chain.
//
// Round-7 mapping: one wave per chain (1024 waves = 1/SIMD). Lane j computes
// ONLY its own gate j (16-FMA dot) -- the round-4/6 4x redundancy is dropped
// because the h all-gather is now cheap DPP (round 6: 422us, 89% VALUBusy,
// issue-bound on the redundant 64-FMA dot + 8 redundant activations).
//   - h lives one-element-per-lane: lane j holds h[j&15] (4 row copies).
//   - 15 DPP row_ror ops give every lane the full h vector in rotated order;
//     weights are per-lane pre-permuted at init (direction probed at runtime).
//   - each lane evaluates ONE activation (sigmoid, or tanh for g-row lanes,
//     selected branchlessly via per-lane a*sig+b constants).
//   - ONE 4-shuffle ds_bpermute exchange gathers {i,f,g,o} at hidden index
//     kp=j&15 (round 1 showed the 4-shuffle exchange is cheap; it was the
//     16-shuffle broadcast that hurt, and that is now DPP).
//   - c, tanh(c), h[kp] computed redundantly on all 4 row copies (local).
// Activation scaling (-log2e; -2log2e for g rows) folded into weights.

#define B_ 1024
#define A_ 16
#define T_ 128
#define R_ 128
#define H_ 16

template<int CTRL>
__device__ __forceinline__ float dpp_rotf(float v) {
    return __int_as_float(__builtin_amdgcn_update_dpp(
        0, __float_as_int(v), CTRL, 0xF, 0xF, true));
}

__global__ __launch_bounds__(64) void lstm_decoder_kernel(
    const float* __restrict__ y,     // (B,16)
    const float* __restrict__ u,     // (B,128)
    const float* __restrict__ W_ih,  // (64,1)
    const float* __restrict__ W_hh,  // (64,16)
    const float* __restrict__ b_ih,  // (64)
    const float* __restrict__ b_hh,  // (64)
    const float* __restrict__ W_lin, // (1,16)
    const float* __restrict__ b_lin, // (1)
    const float* __restrict__ W_h0,  // (16,128)
    const float* __restrict__ b_h0,  // (16)
    const float* __restrict__ W_c0,  // (16,128)
    const float* __restrict__ b_c0,  // (16)
    float* __restrict__ out)         // (B,144)
{
    const int b  = blockIdx.x;    // batch chain
    const int j  = threadIdx.x;   // lane = gate index 0..63
    const int kp = j & 15;        // hidden index this lane carries

    __shared__ float lds_u[R_];
    __shared__ float lds_h[H_];
    __shared__ float lds_c[H_];

    // ---- stage u[b,:] to LDS (coalesced) ----
    lds_u[j]      = u[b * R_ + j];
    lds_u[j + 64] = u[b * R_ + j + 64];
    __syncthreads();

    // ---- h0 / c0 init: lanes 0..15 -> h0[kp], lanes 16..31 -> c0[kp] ----
    if (j < 32) {
        const float* Wr = (j < 16) ? (W_h0 + kp * R_) : (W_c0 + kp * R_);
        float acc = (j < 16) ? b_h0[kp] : b_c0[kp];
        #pragma unroll
        for (int r = 0; r < R_; r += 4) {
            float4 wv = *(const float4*)(Wr + r);
            float4 uv = *(const float4*)(&lds_u[r]);
            acc = fmaf(wv.x, uv.x, acc);
            acc = fmaf(wv.y, uv.y, acc);
            acc = fmaf(wv.z, uv.z, acc);
            acc = fmaf(wv.w, uv.w, acc);
        }
        if (j < 16) lds_h[kp] = acc;
        else        lds_c[kp] = acc;
    }

    // ---- probe DPP row_ror direction (no convention bet) ----
    const int probe = __builtin_amdgcn_update_dpp(0, kp, 0x121, 0xF, 0xF, true);
    const bool plus = (probe == ((kp + 1) & 15));

    // ---- per-lane pre-scaled, pre-permuted weights for gate row j ----
    const float LOG2E = 1.4426950408889634f;
    const bool  isg   = ((j >> 4) == 2);           // rows 32..47 = g gate
    const float sj    = isg ? (-2.0f * LOG2E) : (-LOG2E);
    float w16[H_], wlr[H_];
    #pragma unroll
    for (int r = 0; r < H_; ++r) {
        const int idx = plus ? ((kp + r) & 15) : ((kp - r) & 15);
        w16[r] = sj * W_hh[j * H_ + idx];
        wlr[r] = W_lin[idx];
    }
    const float bj  = sj * (b_ih[j] + b_hh[j]);
    const float wij = sj * W_ih[j];
    const float aAct = isg ? 2.0f : 1.0f;          // act = aAct*sigma + bAct
    const float bAct = isg ? -1.0f : 0.0f;
    const float cK  = -2.0f * LOG2E;               // for tanh(c)
    const float bl  = b_lin[0];

    __syncthreads();
    float hk = lds_h[kp];     // h[kp], replicated across the 4 rows
    float c  = lds_c[kp];     // c[kp]

    float win[A_];
    #pragma unroll
    for (int t = 0; t < A_; ++t) win[t] = y[b * A_ + t];

    float pout0 = 0.f, pout1 = 0.f;

    for (int s = 0; s < T_; ++s) {
        #pragma unroll
        for (int t = 0; t < A_; ++t) {
            const float x = win[t];
            // ---- ONE gate dot per lane via DPP row all-gather ----
            float z0 = fmaf(hk, w16[0], fmaf(x, wij, bj));
            float z1, z2, z3;
            { const float hr = dpp_rotf<0x121>(hk); z1 = hr * w16[1]; }
            { const float hr = dpp_rotf<0x122>(hk); z2 = hr * w16[2]; }
            { const float hr = dpp_rotf<0x123>(hk); z3 = hr * w16[3]; }
#define CELL_ROT(R, CTRL, ACC)                                        \
            { const float hr = dpp_rotf<CTRL>(hk);                    \
              ACC = fmaf(hr, w16[R], ACC); }
            CELL_ROT(4,  0x124, z0)
            CELL_ROT(5,  0x125, z1)
            CELL_ROT(6,  0x126, z2)
            CELL_ROT(7,  0x127, z3)
            CELL_ROT(8,  0x128, z0)
            CELL_ROT(9,  0x129, z1)
            CELL_ROT(10, 0x12A, z2)
            CELL_ROT(11, 0x12B, z3)
            CELL_ROT(12, 0x12C, z0)
            CELL_ROT(13, 0x12D, z1)
            CELL_ROT(14, 0x12E, z2)
            CELL_ROT(15, 0x12F, z3)
#undef CELL_ROT
            const float z = (z0 + z1) + (z2 + z3);

            // ---- own-gate activation only ----
            // i,f,o rows: exp2(z)=e^{-raw}; sigma. g rows: e^{-2raw}; tanh.
            const float e   = __builtin_amdgcn_exp2f(z);
            const float sg  = __builtin_amdgcn_rcpf(1.0f + e);
            const float act = fmaf(aAct, sg, bAct);

            // ---- 4-shuffle gate exchange (the ONLY lgkm event per cell) ----
            const float iv = __shfl(act, kp,      64);
            const float fv = __shfl(act, kp + 16, 64);
            const float gg = __shfl(act, kp + 32, 64);
            const float ov = __shfl(act, kp + 48, 64);

            // ---- c, h[kp] update (redundant on 4 rows, all local) ----
            c = fmaf(fv, c, iv * gg);
            const float ec = __builtin_amdgcn_exp2f(cK * c);                       // e^{-2c}
            const float th = fmaf(2.0f, __builtin_amdgcn_rcpf(1.0f + ec), -1.0f);  // tanh(c)
            hk = ov * th;
        }

        // ---- pred = h . W_lin + b_lin via DPP all-gather ----
        float pa = fmaf(hk, wlr[0], bl);
        float pb;
        { const float hr = dpp_rotf<0x121>(hk); pb = hr * wlr[1]; }
#define PRED_ROT(R, CTRL, ACC)                                        \
        { const float hr = dpp_rotf<CTRL>(hk);                        \
          ACC = fmaf(hr, wlr[R], ACC); }
        PRED_ROT(2,  0x122, pa)
        PRED_ROT(3,  0x123, pb)
        PRED_ROT(4,  0x124, pa)
        PRED_ROT(5,  0x125, pb)
        PRED_ROT(6,  0x126, pa)
        PRED_ROT(7,  0x127, pb)
        PRED_ROT(8,  0x128, pa)
        PRED_ROT(9,  0x129, pb)
        PRED_ROT(10, 0x12A, pa)
        PRED_ROT(11, 0x12B, pb)
        PRED_ROT(12, 0x12C, pa)
        PRED_ROT(13, 0x12D, pb)
        PRED_ROT(14, 0x12E, pa)
        PRED_ROT(15, 0x12F, pb)
#undef PRED_ROT
        const float p = pa + pb;

        // ---- window slide + pred stash ----
        #pragma unroll
        for (int t = 0; t < A_ - 1; ++t) win[t] = win[t + 1];
        win[A_ - 1] = p;
        if (s == j)      pout0 = p;
        if (s == j + 64) pout1 = p;
    }

    // ---- output: out[b,0:16]=y[b,:], out[b,16+s]=pred_s ----
    if (j < A_) out[b * (A_ + T_) + j] = y[b * A_ + j];
    out[b * (A_ + T_) + A_ + j]      = pout0;
    out[b * (A_ + T_) + A_ + 64 + j] = pout1;
}

extern "C" void kernel_launch(void* const* d_in, const int* in_sizes, int n_in,
                              void* d_out, int out_size, void* d_ws, size_t ws_size,
                              hipStream_t stream) {
    const float* y     = (const float*)d_in[0];
    const float* u     = (const float*)d_in[1];
    const float* W_ih  = (const float*)d_in[2];
    const float* W_hh  = (const float*)d_in[3];
    const float* b_ih  = (const float*)d_in[4];
    const float* b_hh  = (const float*)d_in[5];
    const float* W_lin = (const float*)d_in[6];
    const float* b_lin = (const float*)d_in[7];
    const float* W_h0  = (const float*)d_in[8];
    const float* b_h0  = (const float*)d_in[9];
    const float* W_c0  = (const float*)d_in[10];
    const float* b_c0  = (const float*)d_in[11];
    float* out = (float*)d_out;

    lstm_decoder_kernel<<<B_, 64, 0, stream>>>(
        y, u, W_ih, W_hh, b_ih, b_hh, W_lin, b_lin,
        W_h0, b_h0, W_c0, b_c0, out);
}